// Round 2
// baseline (595.426 us; speedup 1.0000x reference)
//
#include <hip/hip_runtime.h>
#include <hip/hip_bf16.h>

// ---------- helpers ----------
__device__ __forceinline__ float bf2f(unsigned short u) {
    union { unsigned int i; float f; } x;
    x.i = ((unsigned int)u) << 16;
    return x.f;
}
__device__ __forceinline__ unsigned short f2bf(float f) {
    union { float f; unsigned int u; } x; x.f = f;
    unsigned int r = x.u + 0x7FFFu + ((x.u >> 16) & 1u);
    return (unsigned short)(r >> 16);
}
__device__ __forceinline__ float fast_tanh(float x) {
    float a = fabsf(x);
    float t = __expf(2.f * a);
    float r = 1.f - 2.f / (t + 1.f);
    return copysignf(r, x);
}
__device__ __forceinline__ int xcc_id() {
    int x;
    // HW_REG_XCC_ID = id 20 on gfx94x/gfx950 (numeric form for assembler safety)
    asm volatile("s_getreg_b32 %0, hwreg(20, 0, 32)" : "=s"(x));
    return x & 7;
}

typedef __bf16    bf16x8 __attribute__((ext_vector_type(8)));
typedef _Float16  f16x8  __attribute__((ext_vector_type(8)));
typedef _Float16  f16x4  __attribute__((ext_vector_type(4)));
typedef float     f32x4  __attribute__((ext_vector_type(4)));

// ---------- workspace byte offsets (total ~110.5 MB) ----------
#define XW_OFF     0UL            // N*256 bf16      = 25,600,000
#define ZB_OFF     25600000UL     // 3N*256 f16      = 76,800,000 (bias folded)
                                  // (bucket-scatter scratch reuses this region
                                  //  before agg_csr writes zb)
#define CSR_OFF    102400000UL    // 3E int32        =  4,800,000
#define RS_OFF     107200000UL    // (3N+1) int32
#define CUR_OFF    107800064UL    // 3N int32
#define BS_OFF     108400128UL    // 256 int32
#define AS_OFF     108401152UL    // N*4 f32
#define AD_OFF     109201152UL    // N*4 f32
#define WT_OFF     110001152UL    // 3*256*256 bf16 (transposed W)
#define W1T_OFF    110394368UL    // 128*256 f16 (transposed w1)
#define ASF_OFF    110459904UL    // 768 f32
#define ADF_OFF    110462976UL
#define BIASF_OFF  110466048UL
#define B1F_OFF    110469120UL
#define W2F_OFF    110469632UL
#define WSUM_OFF   110470144UL
#define BETA_OFF   110470208UL
#define FLAG_OFF   110470272UL

#define CAPX 320                  // per-(xcd,bucket) capacity (mean 128, +17 sigma)

// ---------- P0: dtype probe ----------
__global__ void probe(const unsigned short* __restrict__ hraw,
                      const unsigned int* __restrict__ eraw,
                      int* __restrict__ flags) {
    if (threadIdx.x == 0 && blockIdx.x == 0) {
        int sane = 0;
        for (int i = 0; i < 256; ++i) {
            unsigned int e = (hraw[i] >> 7) & 0xFF;
            if (hraw[i] != 0 && e >= 100 && e <= 150) sane++;
        }
        flags[0] = (sane >= 220) ? 1 : 0;   // 1 = bf16 inputs/outputs
        int zeros = 0;
        for (int i = 1; i < 256; i += 2) if (eraw[i] == 0u) zeros++;
        flags[1] = (zeros >= 120) ? 1 : 0;  // 1 = int64 indices
    }
}

__device__ __forceinline__ float rd_f(const void* p, int j, bool bf) {
    return bf ? bf2f(((const unsigned short*)p)[j]) : ((const float*)p)[j];
}
__device__ __forceinline__ int rd_i(const void* p, long long j, bool i64) {
    return i64 ? (int)((const long long*)p)[j] : ((const int*)p)[j];
}

// ---------- P1: canonicalize params ----------
__global__ void ingest_params(const void* W, const void* as, const void* ad, const void* bias,
                              const void* w1, const void* b1, const void* w2,
                              unsigned short* Wt, _Float16* w1t,
                              float* asf, float* adf, float* biasf,
                              float* b1f, float* w2f,
                              const int* __restrict__ flags) {
    int i = blockIdx.x * 256 + threadIdx.x;
    bool bf = flags[0] != 0;
    if (i < 196608) {                              // Wt[p][n][k] = W[p][k][n]
        int p = i >> 16, n = (i >> 8) & 255, k = i & 255;
        Wt[i] = f2bf(rd_f(W, p * 65536 + k * 256 + n, bf));
    } else if (i < 229376) {                       // w1t[n][k] = w1[k][n], fp16
        int j = i - 196608;
        int n = j >> 8, k = j & 255;
        w1t[j] = (_Float16)rd_f(w1, k * 128 + n, bf);
    } else if (i < 230144) {
        int j = i - 229376; asf[j] = rd_f(as, j, bf);
    } else if (i < 230912) {
        int j = i - 230144; adf[j] = rd_f(ad, j, bf);
    } else if (i < 231680) {
        int j = i - 230912; biasf[j] = rd_f(bias, j, bf);
    } else if (i < 231808) {
        int j = i - 231680; b1f[j] = rd_f(b1, j, bf);
    } else if (i < 231936) {
        int j = i - 231808; w2f[j] = rd_f(w2, j, bf);
    }
}

// ---------- CSR build v2: XCD-local bucket scatter ----------
// bucket = seg >> 7 (128 segments/bucket). 8 XCD-local append streams per
// bucket so each L2 line is written by one XCD only -> full-line writebacks.

// pass1: edges -> XCD-local bucket streams (packed src | low7<<16)
__global__ void bucket_pass1(const void* e0, const void* e1, const void* e2,
                             int* __restrict__ bcnt, unsigned int* __restrict__ bkb,
                             int* __restrict__ scnt, int2* __restrict__ spl,
                             int* __restrict__ cur,
                             int E, int N, int NBUCK, const int* __restrict__ flags) {
    int i = blockIdx.x * 256 + threadIdx.x;
    if (i >= 3 * E) return;
    int p = i / E, e = i - p * E;
    const void* ep = (p == 0) ? e0 : (p == 1) ? e1 : e2;
    bool i64 = flags[1] != 0;
    int src = rd_i(ep, e, i64);
    int dst = rd_i(ep, (long long)E + e, i64);
    int seg = p * N + dst;
    int b = seg >> 7, low = seg & 127;
    int slot = xcc_id() * NBUCK + b;
    int pos = atomicAdd(&bcnt[slot], 1);
    if (pos < CAPX) {
        bkb[(size_t)slot * CAPX + pos] = (unsigned int)src | ((unsigned int)low << 16);
    } else {
        int sp = atomicAdd(scnt, 1);
        spl[sp] = make_int2(src, seg);
        atomicAdd(&cur[seg], 1);      // spill edges counted here; bucket edges in count_buckets
    }
}

// count: per-bucket LDS histogram from the 8 streams -> cur (replaces hist)
__global__ void count_buckets(const int* __restrict__ bcnt,
                              const unsigned int* __restrict__ bkb,
                              int* __restrict__ cur, int M, int NBUCK) {
    __shared__ int cnt[128];
    int b = blockIdx.x, tid = threadIdx.x;
    if (tid < 128) cnt[tid] = 0;
    __syncthreads();
    for (int x = 0; x < 8; ++x) {
        int slot = x * NBUCK + b;
        int n = min(bcnt[slot], CAPX);
        const unsigned int* s = bkb + (size_t)slot * CAPX;
        for (int i = tid; i < n; i += 256) atomicAdd(&cnt[s[i] >> 16], 1);
    }
    __syncthreads();
    if (tid < 128) {
        int seg = b * 128 + tid;
        if (seg < M) cur[seg] += cnt[tid];    // += : spill counts already there
    }
}

__global__ void scan1(const int* __restrict__ cnt, int* __restrict__ rs,
                      int* __restrict__ bs, int M) {
    __shared__ int s[1024];
    int t = threadIdx.x, i = blockIdx.x * 1024 + t;
    int v = (i < M) ? cnt[i] : 0;
    s[t] = v; __syncthreads();
    for (int o = 1; o < 1024; o <<= 1) {
        int tmp = (t >= o) ? s[t - o] : 0;
        __syncthreads();
        s[t] += tmp;
        __syncthreads();
    }
    if (i < M) rs[i] = s[t] - v;
    if (t == 1023) bs[blockIdx.x] = s[t];
}

__global__ void scan2(int* __restrict__ bs, int* __restrict__ rs, int nb, int M) {
    __shared__ int s[256];
    int t = threadIdx.x;
    int v = (t < nb) ? bs[t] : 0;
    s[t] = v; __syncthreads();
    for (int o = 1; o < 256; o <<= 1) {
        int tmp = (t >= o) ? s[t - o] : 0;
        __syncthreads();
        s[t] += tmp;
        __syncthreads();
    }
    if (t < nb) bs[t] = s[t] - v;
    if (t == nb - 1) rs[M] = s[t];
}

__global__ void scan3(int* __restrict__ rs, const int* __restrict__ bs, int M) {
    int i = blockIdx.x * 1024 + threadIdx.x;
    if (i < M) rs[i] += bs[blockIdx.x];
}

// spill place (normally zero work): classic atomic scatter, runs BEFORE pass2
__global__ void spill_place(const int* __restrict__ scnt, const int2* __restrict__ spl,
                            const int* __restrict__ rs, int* __restrict__ cur,
                            int* __restrict__ csr) {
    int total = *scnt;
    for (int i = blockIdx.x * 256 + threadIdx.x; i < total; i += gridDim.x * 256) {
        int2 e = spl[i];
        int pos = rs[e.y] + atomicAdd(&cur[e.y], 1);
        csr[pos] = e.x;
    }
}

// pass2: place bucket edges via 128 LDS cursors -> contiguous csr region/block
__global__ void bucket_pass2(const int* __restrict__ bcnt,
                             const unsigned int* __restrict__ bkb,
                             const int* __restrict__ rs, const int* __restrict__ cur,
                             int* __restrict__ csr, int M, int NBUCK) {
    __shared__ int cursor[128];
    int b = blockIdx.x, tid = threadIdx.x;
    if (tid < 128) {
        int seg = b * 128 + tid;
        cursor[tid] = (seg < M) ? rs[seg] + cur[seg] : 0;   // cur = spill edges placed first
    }
    __syncthreads();
    for (int x = 0; x < 8; ++x) {
        int slot = x * NBUCK + b;
        int n = min(bcnt[slot], CAPX);
        const unsigned int* s = bkb + (size_t)slot * CAPX;
        for (int i = tid; i < n; i += 256) {
            unsigned int u = s[i];
            int pos = atomicAdd(&cursor[u >> 16], 1);
            csr[pos] = (int)(u & 0xFFFFu);
        }
    }
}

// ---------- K1: xw = h @ W[p] (MFMA, B in swizzled LDS, wave = 64r x 128c) ----------
__global__ __launch_bounds__(256, 2)
void gemm_xw_mfma(const void* __restrict__ h,
                  const unsigned short* __restrict__ Wtp,   // [256 n][256 k] bf16
                  unsigned short* __restrict__ xw,
                  const float* __restrict__ asf,            // [256] this path
                  const float* __restrict__ adf,
                  float* __restrict__ as_, float* __restrict__ ad_,
                  const int* __restrict__ flags, int N) {
    __shared__ __bf16 Bs[32768];        // 64 KB: 128 rows x 256 k, 16B-chunk XOR swizzle
    int tid  = threadIdx.x;
    int ch   = blockIdx.x & 1;          // col half
    int rg   = blockIdx.x >> 1;         // row group (256 rows)
    // stage B half into LDS (chunk c of row r -> slot c ^ (r&7))
    {
        const bf16x8* src = (const bf16x8*)Wtp;
#pragma unroll
        for (int it = 0; it < 16; ++it) {
            int c = it * 256 + tid;
            int row = c >> 5, cv = c & 31;
            *(bf16x8*)(Bs + ((row << 5) + (cv ^ (row & 7))) * 8) =
                src[(ch * 128 + row) * 32 + cv];
        }
    }
    __syncthreads();

    int wave = tid >> 6, lane = tid & 63;
    int l15 = lane & 15, quad = lane >> 4;
    int sw  = l15 & 7;
    int row0 = rg * 256 + wave * 64;
    bool bfm = flags[0] != 0;

    int lr[4];
#pragma unroll
    for (int rt = 0; rt < 4; ++rt) lr[rt] = min(row0 + rt * 16 + l15, N - 1);

    f32x4 acc[4][8];
#pragma unroll
    for (int rt = 0; rt < 4; ++rt)
#pragma unroll
        for (int tn = 0; tn < 8; ++tn) acc[rt][tn] = (f32x4){0.f, 0.f, 0.f, 0.f};

#pragma unroll
    for (int c0 = 0; c0 < 32; c0 += 4) {          // k chunk base (16B units), k = c0*8
        int kc = c0 * 8;
        bf16x8 a[4];
#pragma unroll
        for (int rt = 0; rt < 4; ++rt) {
            size_t off = (size_t)lr[rt] * 256 + kc + quad * 8;
            if (bfm) {
                a[rt] = *reinterpret_cast<const bf16x8*>((const __bf16*)h + off);
            } else {
                f32x4 u0 = *reinterpret_cast<const f32x4*>((const float*)h + off);
                f32x4 u1 = *reinterpret_cast<const f32x4*>((const float*)h + off + 4);
#pragma unroll
                for (int j = 0; j < 4; ++j) { a[rt][j] = (__bf16)u0[j]; a[rt][4 + j] = (__bf16)u1[j]; }
            }
        }
#pragma unroll
        for (int tn = 0; tn < 8; ++tn) {
            int row = tn * 16 + l15;
            bf16x8 b = *reinterpret_cast<const bf16x8*>(
                Bs + ((row << 5) + (((c0 + quad)) ^ sw)) * 8);
#pragma unroll
            for (int rt = 0; rt < 4; ++rt)
                acc[rt][tn] = __builtin_amdgcn_mfma_f32_16x16x32_bf16(a[rt], b, acc[rt][tn], 0, 0, 0);
        }
    }

    // epilogue: store xw + fused alpha (wave owns heads {2ch, 2ch+1})
#pragma unroll
    for (int rt = 0; rt < 4; ++rt) {
        int rbase = row0 + rt * 16 + quad * 4;
#pragma unroll
        for (int tn = 0; tn < 8; ++tn) {
            int c = ch * 128 + tn * 16 + l15;
#pragma unroll
            for (int i = 0; i < 4; ++i) {
                int r = rbase + i;
                if (r < N) xw[(size_t)r * 256 + c] = f2bf(acc[rt][tn][i]);
            }
        }
        float ss[2][4] = {{0.f,0.f,0.f,0.f},{0.f,0.f,0.f,0.f}};
        float dd[2][4] = {{0.f,0.f,0.f,0.f},{0.f,0.f,0.f,0.f}};
#pragma unroll
        for (int tn = 0; tn < 8; ++tn) {
            int c = ch * 128 + tn * 16 + l15;
            float sv = asf[c], dv = adf[c];
            int hs = tn >> 2;
#pragma unroll
            for (int i = 0; i < 4; ++i) {
                ss[hs][i] += acc[rt][tn][i] * sv;
                dd[hs][i] += acc[rt][tn][i] * dv;
            }
        }
#pragma unroll
        for (int hs = 0; hs < 2; ++hs)
#pragma unroll
            for (int i = 0; i < 4; ++i) {
                float s = ss[hs][i], d = dd[hs][i];
                s += __shfl_xor(s, 1); d += __shfl_xor(d, 1);
                s += __shfl_xor(s, 2); d += __shfl_xor(d, 2);
                s += __shfl_xor(s, 4); d += __shfl_xor(d, 4);
                s += __shfl_xor(s, 8); d += __shfl_xor(d, 8);
                ss[hs][i] = s; dd[hs][i] = d;
            }
        if (l15 == 0) {
#pragma unroll
            for (int hs = 0; hs < 2; ++hs)
#pragma unroll
                for (int i = 0; i < 4; ++i) {
                    int r = rbase + i;
                    if (r < N) {
                        int g = r * 4 + ch * 2 + hs;
                        as_[g] = ss[hs][i];
                        ad_[g] = dd[hs][i];
                    }
                }
        }
    }
}

__device__ __forceinline__ float leaky(float v) { return v > 0.f ? v : 0.2f * v; }

// ---------- K5: CSR online-softmax aggregate -> z' fp16 (bias folded) ----------
__global__ void agg_csr(const int* __restrict__ csr, const int* __restrict__ rs,
                        const float* __restrict__ as_, const float* __restrict__ ad_,
                        const unsigned short* __restrict__ xw,
                        const float* __restrict__ biasf,
                        _Float16* __restrict__ zb, int N, int p) {
    int d = blockIdx.x * 4 + (threadIdx.x >> 6);
    if (d >= N) return;
    int lane = threadIdx.x & 63;
    int h = lane >> 4;
    int seg = p * N + d;
    int start = rs[seg], end = rs[seg + 1];

    float adh = ad_[d * 4 + h];
    float m = leaky(as_[d * 4 + h] + adh);
    float l = 1.f;
    float a0, a1, a2, a3;
    {
        ushort4 u = *reinterpret_cast<const ushort4*>(xw + (size_t)d * 256 + lane * 4);
        a0 = bf2f(u.x); a1 = bf2f(u.y); a2 = bf2f(u.z); a3 = bf2f(u.w);
    }
    int srcA = (start < end) ? csr[start] : 0;
    for (int j = start; j < end; ++j) {
        int srcB = (j + 1 < end) ? csr[j + 1] : 0;
        float v = leaky(as_[srcA * 4 + h] + adh);
        ushort4 u = *reinterpret_cast<const ushort4*>(xw + (size_t)srcA * 256 + lane * 4);
        float mn = fmaxf(m, v);
        float c = __expf(m - mn);
        float w = __expf(v - mn);
        m = mn;
        l = l * c + w;
        a0 = a0 * c + w * bf2f(u.x);
        a1 = a1 * c + w * bf2f(u.y);
        a2 = a2 * c + w * bf2f(u.z);
        a3 = a3 * c + w * bf2f(u.w);
        srcA = srcB;
    }
    float inv = 1.f / l;
    int col = lane * 4;
    const float* bp = biasf + p * 256 + col;
    f16x4 o = {(_Float16)(a0 * inv + bp[0]), (_Float16)(a1 * inv + bp[1]),
               (_Float16)(a2 * inv + bp[2]), (_Float16)(a3 * inv + bp[3])};
    *reinterpret_cast<f16x4*>(zb + ((size_t)d * 3 + p) * 256 + col) = o;
}

// ---------- K6: semantic attention (f16 MFMA, w1 in swizzled LDS) ----------
// 1024-thread blocks (16 waves, 16 rows/wave): 64 KB w1 tile serves 16 waves,
// 2 blocks/CU -> 32 waves/CU.
__global__ __launch_bounds__(1024, 4)
void sem_w_mfma(const _Float16* __restrict__ zb,
                const _Float16* __restrict__ w1t,   // [128 n][256 k] f16
                const float* __restrict__ b1f,
                const float* __restrict__ w2f,
                float* __restrict__ wsum, int rows) {
    __shared__ _Float16 Bs[32768];      // 64 KB, 16B-chunk XOR swizzle
    __shared__ float redbuf[16][3];     // per-wave bins for block reduction
    int tid = threadIdx.x;
    {
        const f16x8* src = (const f16x8*)w1t;
#pragma unroll
        for (int it = 0; it < 4; ++it) {
            int c = it * 1024 + tid;
            int row = c >> 5, cv = c & 31;
            *(f16x8*)(Bs + ((row << 5) + (cv ^ (row & 7))) * 8) = src[c];
        }
    }
    __syncthreads();

    int wave = tid >> 6, lane = tid & 63;
    int l15 = lane & 15, quad = lane >> 4;
    int sw  = l15 & 7;
    int row0 = blockIdx.x * 256 + wave * 16;
    int lr = min(row0 + l15, rows - 1);

    f32x4 acc[8];
#pragma unroll
    for (int tn = 0; tn < 8; ++tn) acc[tn] = (f32x4){0.f, 0.f, 0.f, 0.f};

#pragma unroll
    for (int c0 = 0; c0 < 32; c0 += 4) {
        int kc = c0 * 8;
        f16x8 a = *reinterpret_cast<const f16x8*>(zb + (size_t)lr * 256 + kc + quad * 8);
#pragma unroll
        for (int tn = 0; tn < 8; ++tn) {
            int brow = tn * 16 + l15;
            f16x8 b = *reinterpret_cast<const f16x8*>(
                Bs + ((brow << 5) + ((c0 + quad) ^ sw)) * 8);
            acc[tn] = __builtin_amdgcn_mfma_f32_16x16x32_f16(a, b, acc[tn], 0, 0, 0);
        }
    }

    // epilogue: per-row tanh-dot, reduce over hidden (l15), bin by row%3
    float rowsum[4] = {0.f, 0.f, 0.f, 0.f};
#pragma unroll
    for (int tn = 0; tn < 8; ++tn) {
        int col = tn * 16 + l15;
        float b1v = b1f[col], w2v = w2f[col];
#pragma unroll
        for (int i = 0; i < 4; ++i)
            rowsum[i] += fast_tanh(acc[tn][i] + b1v) * w2v;
    }
#pragma unroll
    for (int i = 0; i < 4; ++i) {
        rowsum[i] += __shfl_xor(rowsum[i], 1);
        rowsum[i] += __shfl_xor(rowsum[i], 2);
        rowsum[i] += __shfl_xor(rowsum[i], 4);
        rowsum[i] += __shfl_xor(rowsum[i], 8);
    }
    float bins[3] = {0.f, 0.f, 0.f};
    if (l15 == 0) {
#pragma unroll
        for (int i = 0; i < 4; ++i) {
            int r = row0 + quad * 4 + i;
            if (r < rows) bins[r % 3] += rowsum[i];
        }
    }
#pragma unroll
    for (int b = 0; b < 3; ++b) {   // combine the 4 quads (lanes 0,16,32,48)
        bins[b] += __shfl_xor(bins[b], 16);
        bins[b] += __shfl_xor(bins[b], 32);
    }
    if (lane == 0) {
#pragma unroll
        for (int b = 0; b < 3; ++b) redbuf[wave][b] = bins[b];
    }
    __syncthreads();
    if (tid < 3) {                  // block-level reduce: 3 atomics per block
        float s = 0.f;
#pragma unroll
        for (int w = 0; w < 16; ++w) s += redbuf[w][tid];
        atomicAdd(&wsum[tid], s);
    }
}

// ---------- K7: beta = softmax(mean) ----------
__global__ void beta_kernel(const float* __restrict__ wsum, float* __restrict__ beta, float invN) {
    if (threadIdx.x == 0) {
        float w0 = wsum[0] * invN, w1 = wsum[1] * invN, w2 = wsum[2] * invN;
        float mx = fmaxf(w0, fmaxf(w1, w2));
        float e0 = __expf(w0 - mx), e1 = __expf(w1 - mx), e2 = __expf(w2 - mx);
        float s = e0 + e1 + e2;
        beta[0] = e0 / s; beta[1] = e1 / s; beta[2] = e2 / s;
    }
}

// ---------- K8: out = sum_p beta[p]*z'[:,p,:] ----------
__global__ void combine(const _Float16* __restrict__ zb,
                        const float* __restrict__ beta,
                        void* __restrict__ out, const int* __restrict__ flags) {
    int idx = blockIdx.x * 256 + threadIdx.x;    // over N*64
    int n = idx >> 6, c4 = (idx & 63) * 4;
    float b0 = beta[0], b1 = beta[1], b2 = beta[2];
    const _Float16* base = zb + (size_t)n * 768 + c4;
    f16x4 z0 = *reinterpret_cast<const f16x4*>(base);
    f16x4 z1 = *reinterpret_cast<const f16x4*>(base + 256);
    f16x4 z2 = *reinterpret_cast<const f16x4*>(base + 512);
    float v[4];
#pragma unroll
    for (int i = 0; i < 4; ++i)
        v[i] = b0 * (float)z0[i] + b1 * (float)z1[i] + b2 * (float)z2[i];
    if (flags[0]) {
        ushort4 o = {f2bf(v[0]), f2bf(v[1]), f2bf(v[2]), f2bf(v[3])};
        *reinterpret_cast<ushort4*>((unsigned short*)out + (size_t)idx * 4) = o;
    } else {
        f32x4 o = {v[0], v[1], v[2], v[3]};
        *reinterpret_cast<f32x4*>((float*)out + (size_t)idx * 4) = o;
    }
}

extern "C" void kernel_launch(void* const* d_in, const int* in_sizes, int n_in,
                              void* d_out, int out_size, void* d_ws, size_t ws_size,
                              hipStream_t stream) {
    const void* h    = d_in[0];
    const void* e0   = d_in[1];
    const void* e1   = d_in[2];
    const void* e2   = d_in[3];
    const void* W    = d_in[4];
    const void* as   = d_in[5];
    const void* ad   = d_in[6];
    const void* bias = d_in[7];
    const void* w1   = d_in[8];
    const void* b1   = d_in[9];
    const void* w2   = d_in[10];

    const int N = in_sizes[0] / 256;   // 50000
    const int E = in_sizes[1] / 2;     // 400000
    const int M = 3 * N;               // 150000 segments
    const int NBUCK = (M + 127) >> 7;  // 1172 buckets of 128 segments

    char* ws = (char*)d_ws;
    unsigned short* xw    = (unsigned short*)(ws + XW_OFF);
    _Float16*       zb    = (_Float16*)(ws + ZB_OFF);
    int*            csr   = (int*)(ws + CSR_OFF);
    int*            rs    = (int*)(ws + RS_OFF);
    int*            cur   = (int*)(ws + CUR_OFF);
    int*            bs    = (int*)(ws + BS_OFF);
    float*          as_   = (float*)(ws + AS_OFF);
    float*          ad_   = (float*)(ws + AD_OFF);
    unsigned short* Wt    = (unsigned short*)(ws + WT_OFF);
    _Float16*       w1t   = (_Float16*)(ws + W1T_OFF);
    float*          asf   = (float*)(ws + ASF_OFF);
    float*          adf   = (float*)(ws + ADF_OFF);
    float*          biasf = (float*)(ws + BIASF_OFF);
    float*          b1f   = (float*)(ws + B1F_OFF);
    float*          w2f   = (float*)(ws + W2F_OFF);
    float*          wsum  = (float*)(ws + WSUM_OFF);
    float*          beta  = (float*)(ws + BETA_OFF);
    int*            flags = (int*)(ws + FLAG_OFF);

    // bucket-scatter scratch overlays the zb region (dead until agg_csr)
    unsigned int* bkb  = (unsigned int*)(ws + ZB_OFF);               // 8*NBUCK*CAPX u32 = 12.0 MB
    int2*         spl  = (int2*)(ws + ZB_OFF + (size_t)8 * NBUCK * CAPX * 4);  // 3E int2 = 9.6 MB
    int*          bcnt = (int*)((char*)spl + (size_t)3 * E * 8);     // 8*NBUCK int
    int*          scnt = bcnt + 8 * NBUCK;                           // 1 int

    probe<<<1, 64, 0, stream>>>((const unsigned short*)h, (const unsigned int*)e0, flags);
    ingest_params<<<907, 256, 0, stream>>>(W, as, ad, bias, w1, b1, w2,
                                           Wt, w1t, asf, adf, biasf, b1f, w2f, flags);

    // CSR build v2
    int nb = (M + 1023) / 1024;                    // 147
    int eB = (3 * E + 255) / 256;                  // 4688
    hipMemsetAsync(cur, 0, M * sizeof(int), stream);
    hipMemsetAsync(bcnt, 0, (8 * NBUCK + 1) * sizeof(int), stream);
    bucket_pass1<<<eB, 256, 0, stream>>>(e0, e1, e2, bcnt, bkb, scnt, spl, cur, E, N, NBUCK, flags);
    count_buckets<<<NBUCK, 256, 0, stream>>>(bcnt, bkb, cur, M, NBUCK);
    scan1<<<nb, 1024, 0, stream>>>(cur, rs, bs, M);
    scan2<<<1, 256, 0, stream>>>(bs, rs, nb, M);
    scan3<<<nb, 1024, 0, stream>>>(rs, bs, M);
    hipMemsetAsync(cur, 0, M * sizeof(int), stream);
    spill_place<<<64, 256, 0, stream>>>(scnt, spl, rs, cur, csr);
    bucket_pass2<<<NBUCK, 256, 0, stream>>>(bcnt, bkb, rs, cur, csr, M, NBUCK);

    hipMemsetAsync(wsum, 0, 16, stream);

    int gemmBlocks = ((N + 255) / 256) * 2;        // 392
    int aggBlocks  = (N + 3) / 4;                  // 12500
    for (int p = 0; p < 3; ++p) {
        gemm_xw_mfma<<<gemmBlocks, 256, 0, stream>>>(h, Wt + p * 65536, xw,
                                                     asf + p * 256, adf + p * 256,
                                                     as_, ad_, flags, N);
        agg_csr<<<aggBlocks, 256, 0, stream>>>(csr, rs, as_, ad_, xw, biasf, zb, N, p);
    }

    int semBlocks = (M + 255) / 256;               // 586
    sem_w_mfma<<<semBlocks, 1024, 0, stream>>>(zb, w1t, b1f, w2f, wsum, M);
    beta_kernel<<<1, 64, 0, stream>>>(wsum, beta, 1.0f / (float)N);
    combine<<<(N * 64 + 255) / 256, 256, 0, stream>>>(zb, beta, d_out, flags);
}

// Round 4
// 531.277 us; speedup vs baseline: 1.1207x; 1.1207x over previous
//
#include <hip/hip_runtime.h>
#include <hip/hip_bf16.h>

// ---------- helpers ----------
__device__ __forceinline__ float bf2f(unsigned short u) {
    union { unsigned int i; float f; } x;
    x.i = ((unsigned int)u) << 16;
    return x.f;
}
__device__ __forceinline__ unsigned short f2bf(float f) {
    union { float f; unsigned int u; } x; x.f = f;
    unsigned int r = x.u + 0x7FFFu + ((x.u >> 16) & 1u);
    return (unsigned short)(r >> 16);
}
__device__ __forceinline__ float fast_tanh(float x) {
    float a = fabsf(x);
    float t = __expf(2.f * a);
    float r = 1.f - 2.f / (t + 1.f);
    return copysignf(r, x);
}

typedef __bf16    bf16x8 __attribute__((ext_vector_type(8)));
typedef _Float16  f16x8  __attribute__((ext_vector_type(8)));
typedef _Float16  f16x4  __attribute__((ext_vector_type(4)));
typedef float     f32x4  __attribute__((ext_vector_type(4)));

// ---------- workspace byte offsets (total ~110.5 MB) ----------
#define XW_OFF     0UL            // N*256 bf16      = 25,600,000
#define ZB_OFF     25600000UL     // 3N*256 f16      = 76,800,000 (bias folded)
                                  // (packed-edge scratch reuses this region
                                  //  before agg_csr writes zb)
#define CSR_OFF    102400000UL    // 3E u16          =  2,400,000
#define RS_OFF     107200000UL    // (3N+1) int32
#define CUR_OFF    107800064UL    // 3N int32
#define BS_OFF     108400128UL    // 256 int32
#define AS_OFF     108401152UL    // N*4 f32
#define AD_OFF     109201152UL    // N*4 f32
#define WT_OFF     110001152UL    // 3*256*256 bf16 (transposed W)
#define W1T_OFF    110394368UL    // 128*256 f16 (transposed w1)
#define ASF_OFF    110459904UL    // 768 f32
#define ADF_OFF    110462976UL
#define BIASF_OFF  110466048UL
#define B1F_OFF    110469120UL
#define W2F_OFF    110469632UL
#define WSUM_OFF   110470144UL
#define BETA_OFF   110470208UL
#define FLAG_OFF   110470272UL

// ---------- P0: dtype probe ----------
__global__ void probe(const unsigned short* __restrict__ hraw,
                      const unsigned int* __restrict__ eraw,
                      int* __restrict__ flags) {
    if (threadIdx.x == 0 && blockIdx.x == 0) {
        int sane = 0;
        for (int i = 0; i < 256; ++i) {
            unsigned int e = (hraw[i] >> 7) & 0xFF;
            if (hraw[i] != 0 && e >= 100 && e <= 150) sane++;
        }
        flags[0] = (sane >= 220) ? 1 : 0;   // 1 = bf16 inputs/outputs
        int zeros = 0;
        for (int i = 1; i < 256; i += 2) if (eraw[i] == 0u) zeros++;
        flags[1] = (zeros >= 120) ? 1 : 0;  // 1 = int64 indices
    }
}

__device__ __forceinline__ float rd_f(const void* p, int j, bool bf) {
    return bf ? bf2f(((const unsigned short*)p)[j]) : ((const float*)p)[j];
}
__device__ __forceinline__ int rd_i(const void* p, long long j, bool i64) {
    return i64 ? (int)((const long long*)p)[j] : ((const int*)p)[j];
}

// ---------- P1: canonicalize params ----------
__global__ void ingest_params(const void* W, const void* as, const void* ad, const void* bias,
                              const void* w1, const void* b1, const void* w2,
                              unsigned short* Wt, _Float16* w1t,
                              float* asf, float* adf, float* biasf,
                              float* b1f, float* w2f,
                              const int* __restrict__ flags) {
    int i = blockIdx.x * 256 + threadIdx.x;
    bool bf = flags[0] != 0;
    if (i < 196608) {                              // Wt[p][n][k] = W[p][k][n]
        int p = i >> 16, n = (i >> 8) & 255, k = i & 255;
        Wt[i] = f2bf(rd_f(W, p * 65536 + k * 256 + n, bf));
    } else if (i < 229376) {                       // w1t[n][k] = w1[k][n], fp16
        int j = i - 196608;
        int n = j >> 8, k = j & 255;
        w1t[j] = (_Float16)rd_f(w1, k * 128 + n, bf);
    } else if (i < 230144) {
        int j = i - 229376; asf[j] = rd_f(as, j, bf);
    } else if (i < 230912) {
        int j = i - 230144; adf[j] = rd_f(ad, j, bf);
    } else if (i < 231680) {
        int j = i - 230912; biasf[j] = rd_f(bias, j, bf);
    } else if (i < 231808) {
        int j = i - 231680; b1f[j] = rd_f(b1, j, bf);
    } else if (i < 231936) {
        int j = i - 231808; w2f[j] = rd_f(w2, j, bf);
    }
}

// ---------- CSR build v3: pack edges u32 + hist in one pass, u16 csr ----------
// conv_hist: read int64 edges once, emit packed (src | dst<<16), histogram cur.
// 4 edges/thread (independent chains -> 4x memory-level parallelism).
// NOTE: i >= T4 guard is essential — extra threads would duplicate edges.
__global__ void conv_hist(const void* e0, const void* e1, const void* e2,
                          unsigned int* __restrict__ ed, int* __restrict__ cur,
                          int E, int N, int T4, const int* __restrict__ flags) {
    int i = blockIdx.x * 256 + threadIdx.x;
    if (i >= T4) return;
    bool i64 = flags[1] != 0;
    int tot = 3 * E;
#pragma unroll
    for (int c = 0; c < 4; ++c) {
        int idx = i + c * T4;
        if (idx >= tot) continue;
        int p = idx / E, e = idx - p * E;
        const void* ep = (p == 0) ? e0 : (p == 1) ? e1 : e2;
        unsigned int src = (unsigned int)rd_i(ep, e, i64);
        unsigned int dst = (unsigned int)rd_i(ep, (long long)E + e, i64);
        ed[idx] = src | (dst << 16);
        atomicAdd(&cur[p * N + (int)dst], 1);
    }
}

__global__ void scan1(const int* __restrict__ cnt, int* __restrict__ rs,
                      int* __restrict__ bs, int M) {
    __shared__ int s[1024];
    int t = threadIdx.x, i = blockIdx.x * 1024 + t;
    int v = (i < M) ? cnt[i] : 0;
    s[t] = v; __syncthreads();
    for (int o = 1; o < 1024; o <<= 1) {
        int tmp = (t >= o) ? s[t - o] : 0;
        __syncthreads();
        s[t] += tmp;
        __syncthreads();
    }
    if (i < M) rs[i] = s[t] - v;
    if (t == 1023) bs[blockIdx.x] = s[t];
}

__global__ void scan2(int* __restrict__ bs, int* __restrict__ rs, int nb, int M) {
    __shared__ int s[256];
    int t = threadIdx.x;
    int v = (t < nb) ? bs[t] : 0;
    s[t] = v; __syncthreads();
    for (int o = 1; o < 256; o <<= 1) {
        int tmp = (t >= o) ? s[t - o] : 0;
        __syncthreads();
        s[t] += tmp;
        __syncthreads();
    }
    if (t < nb) bs[t] = s[t] - v;
    if (t == nb - 1) rs[M] = s[t];
}

__global__ void scan3(int* __restrict__ rs, const int* __restrict__ bs, int M) {
    int i = blockIdx.x * 1024 + threadIdx.x;
    if (i < M) rs[i] += bs[blockIdx.x];
}

// scatter: packed edges (coalesced u32 reads) -> u16 csr, 4 edges/thread
__global__ void scatter(const unsigned int* __restrict__ ed,
                        const int* __restrict__ rs, int* __restrict__ cur,
                        unsigned short* __restrict__ csr, int E, int N, int T4) {
    int i = blockIdx.x * 256 + threadIdx.x;
    if (i >= T4) return;
    int tot = 3 * E;
#pragma unroll
    for (int c = 0; c < 4; ++c) {
        int idx = i + c * T4;
        if (idx >= tot) continue;
        unsigned int u = ed[idx];
        int p = idx / E;
        int seg = p * N + (int)(u >> 16);
        int pos = rs[seg] + atomicAdd(&cur[seg], 1);
        csr[pos] = (unsigned short)(u & 0xFFFFu);
    }
}

// ---------- K1: xw = h @ W[p] (MFMA, B in swizzled LDS, wave = 64r x 128c) ----------
__global__ __launch_bounds__(256, 2)
void gemm_xw_mfma(const void* __restrict__ h,
                  const unsigned short* __restrict__ Wtp,   // [256 n][256 k] bf16
                  unsigned short* __restrict__ xw,
                  const float* __restrict__ asf,            // [256] this path
                  const float* __restrict__ adf,
                  float* __restrict__ as_, float* __restrict__ ad_,
                  const int* __restrict__ flags, int N) {
    __shared__ __bf16 Bs[32768];        // 64 KB: 128 rows x 256 k, 16B-chunk XOR swizzle
    int tid  = threadIdx.x;
    int ch   = blockIdx.x & 1;          // col half
    int rg   = blockIdx.x >> 1;         // row group (256 rows)
    // stage B half into LDS (chunk c of row r -> slot c ^ (r&7))
    {
        const bf16x8* src = (const bf16x8*)Wtp;
#pragma unroll
        for (int it = 0; it < 16; ++it) {
            int c = it * 256 + tid;
            int row = c >> 5, cv = c & 31;
            *(bf16x8*)(Bs + ((row << 5) + (cv ^ (row & 7))) * 8) =
                src[(ch * 128 + row) * 32 + cv];
        }
    }
    __syncthreads();

    int wave = tid >> 6, lane = tid & 63;
    int l15 = lane & 15, quad = lane >> 4;
    int sw  = l15 & 7;
    int row0 = rg * 256 + wave * 64;
    bool bfm = flags[0] != 0;

    int lr[4];
#pragma unroll
    for (int rt = 0; rt < 4; ++rt) lr[rt] = min(row0 + rt * 16 + l15, N - 1);

    f32x4 acc[4][8];
#pragma unroll
    for (int rt = 0; rt < 4; ++rt)
#pragma unroll
        for (int tn = 0; tn < 8; ++tn) acc[rt][tn] = (f32x4){0.f, 0.f, 0.f, 0.f};

#pragma unroll
    for (int c0 = 0; c0 < 32; c0 += 4) {          // k chunk base (16B units), k = c0*8
        int kc = c0 * 8;
        bf16x8 a[4];
#pragma unroll
        for (int rt = 0; rt < 4; ++rt) {
            size_t off = (size_t)lr[rt] * 256 + kc + quad * 8;
            if (bfm) {
                a[rt] = *reinterpret_cast<const bf16x8*>((const __bf16*)h + off);
            } else {
                f32x4 u0 = *reinterpret_cast<const f32x4*>((const float*)h + off);
                f32x4 u1 = *reinterpret_cast<const f32x4*>((const float*)h + off + 4);
#pragma unroll
                for (int j = 0; j < 4; ++j) { a[rt][j] = (__bf16)u0[j]; a[rt][4 + j] = (__bf16)u1[j]; }
            }
        }
#pragma unroll
        for (int tn = 0; tn < 8; ++tn) {
            int row = tn * 16 + l15;
            bf16x8 b = *reinterpret_cast<const bf16x8*>(
                Bs + ((row << 5) + (((c0 + quad)) ^ sw)) * 8);
#pragma unroll
            for (int rt = 0; rt < 4; ++rt)
                acc[rt][tn] = __builtin_amdgcn_mfma_f32_16x16x32_bf16(a[rt], b, acc[rt][tn], 0, 0, 0);
        }
    }

    // epilogue: store xw + fused alpha (wave owns heads {2ch, 2ch+1})
#pragma unroll
    for (int rt = 0; rt < 4; ++rt) {
        int rbase = row0 + rt * 16 + quad * 4;
#pragma unroll
        for (int tn = 0; tn < 8; ++tn) {
            int c = ch * 128 + tn * 16 + l15;
#pragma unroll
            for (int i = 0; i < 4; ++i) {
                int r = rbase + i;
                if (r < N) xw[(size_t)r * 256 + c] = f2bf(acc[rt][tn][i]);
            }
        }
        float ss[2][4] = {{0.f,0.f,0.f,0.f},{0.f,0.f,0.f,0.f}};
        float dd[2][4] = {{0.f,0.f,0.f,0.f},{0.f,0.f,0.f,0.f}};
#pragma unroll
        for (int tn = 0; tn < 8; ++tn) {
            int c = ch * 128 + tn * 16 + l15;
            float sv = asf[c], dv = adf[c];
            int hs = tn >> 2;
#pragma unroll
            for (int i = 0; i < 4; ++i) {
                ss[hs][i] += acc[rt][tn][i] * sv;
                dd[hs][i] += acc[rt][tn][i] * dv;
            }
        }
#pragma unroll
        for (int hs = 0; hs < 2; ++hs)
#pragma unroll
            for (int i = 0; i < 4; ++i) {
                float s = ss[hs][i], d = dd[hs][i];
                s += __shfl_xor(s, 1); d += __shfl_xor(d, 1);
                s += __shfl_xor(s, 2); d += __shfl_xor(d, 2);
                s += __shfl_xor(s, 4); d += __shfl_xor(d, 4);
                s += __shfl_xor(s, 8); d += __shfl_xor(d, 8);
                ss[hs][i] = s; dd[hs][i] = d;
            }
        if (l15 == 0) {
#pragma unroll
            for (int hs = 0; hs < 2; ++hs)
#pragma unroll
                for (int i = 0; i < 4; ++i) {
                    int r = rbase + i;
                    if (r < N) {
                        int g = r * 4 + ch * 2 + hs;
                        as_[g] = ss[hs][i];
                        ad_[g] = dd[hs][i];
                    }
                }
        }
    }
}

__device__ __forceinline__ float leaky(float v) { return v > 0.f ? v : 0.2f * v; }

// ---------- K5: CSR online-softmax aggregate -> z' fp16 (bias folded) ----------
// u16 csr; one-iteration software-pipeline lookahead on score + row loads.
__global__ void agg_csr(const unsigned short* __restrict__ csr, const int* __restrict__ rs,
                        const float* __restrict__ as_, const float* __restrict__ ad_,
                        const unsigned short* __restrict__ xw,
                        const float* __restrict__ biasf,
                        _Float16* __restrict__ zb, int N, int p) {
    int d = blockIdx.x * 4 + (threadIdx.x >> 6);
    if (d >= N) return;
    int lane = threadIdx.x & 63;
    int h = lane >> 4;
    int seg = p * N + d;
    int start = rs[seg], end = rs[seg + 1];

    float adh = ad_[d * 4 + h];
    float m = leaky(as_[d * 4 + h] + adh);
    float l = 1.f;
    float a0, a1, a2, a3;
    {
        ushort4 u = *reinterpret_cast<const ushort4*>(xw + (size_t)d * 256 + lane * 4);
        a0 = bf2f(u.x); a1 = bf2f(u.y); a2 = bf2f(u.z); a3 = bf2f(u.w);
    }
    if (start < end) {
        int srcA = csr[start];
        float sA = as_[srcA * 4 + h];
        ushort4 uA = *reinterpret_cast<const ushort4*>(xw + (size_t)srcA * 256 + lane * 4);
        for (int j = start; j < end; ++j) {
            // issue next-neighbor loads before this iteration's math
            int srcB = (j + 1 < end) ? csr[j + 1] : 0;
            float sB = as_[srcB * 4 + h];
            ushort4 uB = *reinterpret_cast<const ushort4*>(xw + (size_t)srcB * 256 + lane * 4);
            float v = leaky(sA + adh);
            float mn = fmaxf(m, v);
            float c = __expf(m - mn);
            float w = __expf(v - mn);
            m = mn;
            l = l * c + w;
            a0 = a0 * c + w * bf2f(uA.x);
            a1 = a1 * c + w * bf2f(uA.y);
            a2 = a2 * c + w * bf2f(uA.z);
            a3 = a3 * c + w * bf2f(uA.w);
            sA = sB; uA = uB;
        }
    }
    float inv = 1.f / l;
    int col = lane * 4;
    const float* bp = biasf + p * 256 + col;
    f16x4 o = {(_Float16)(a0 * inv + bp[0]), (_Float16)(a1 * inv + bp[1]),
               (_Float16)(a2 * inv + bp[2]), (_Float16)(a3 * inv + bp[3])};
    *reinterpret_cast<f16x4*>(zb + ((size_t)d * 3 + p) * 256 + col) = o;
}

// ---------- K6: semantic attention (f16 MFMA, w1 in swizzled LDS) ----------
// 1024-thread blocks (16 waves, 16 rows/wave): 64 KB w1 tile serves 16 waves,
// 2 blocks/CU -> 32 waves/CU.
__global__ __launch_bounds__(1024, 4)
void sem_w_mfma(const _Float16* __restrict__ zb,
                const _Float16* __restrict__ w1t,   // [128 n][256 k] f16
                const float* __restrict__ b1f,
                const float* __restrict__ w2f,
                float* __restrict__ wsum, int rows) {
    __shared__ _Float16 Bs[32768];      // 64 KB, 16B-chunk XOR swizzle
    __shared__ float redbuf[16][3];     // per-wave bins for block reduction
    int tid = threadIdx.x;
    {
        const f16x8* src = (const f16x8*)w1t;
#pragma unroll
        for (int it = 0; it < 4; ++it) {
            int c = it * 1024 + tid;
            int row = c >> 5, cv = c & 31;
            *(f16x8*)(Bs + ((row << 5) + (cv ^ (row & 7))) * 8) = src[c];
        }
    }
    __syncthreads();

    int wave = tid >> 6, lane = tid & 63;
    int l15 = lane & 15, quad = lane >> 4;
    int sw  = l15 & 7;
    int row0 = blockIdx.x * 256 + wave * 16;
    int lr = min(row0 + l15, rows - 1);

    f32x4 acc[8];
#pragma unroll
    for (int tn = 0; tn < 8; ++tn) acc[tn] = (f32x4){0.f, 0.f, 0.f, 0.f};

#pragma unroll
    for (int c0 = 0; c0 < 32; c0 += 4) {
        int kc = c0 * 8;
        f16x8 a = *reinterpret_cast<const f16x8*>(zb + (size_t)lr * 256 + kc + quad * 8);
#pragma unroll
        for (int tn = 0; tn < 8; ++tn) {
            int brow = tn * 16 + l15;
            f16x8 b = *reinterpret_cast<const f16x8*>(
                Bs + ((brow << 5) + ((c0 + quad) ^ sw)) * 8);
            acc[tn] = __builtin_amdgcn_mfma_f32_16x16x32_f16(a, b, acc[tn], 0, 0, 0);
        }
    }

    // epilogue: per-row tanh-dot, reduce over hidden (l15), bin by row%3
    float rowsum[4] = {0.f, 0.f, 0.f, 0.f};
#pragma unroll
    for (int tn = 0; tn < 8; ++tn) {
        int col = tn * 16 + l15;
        float b1v = b1f[col], w2v = w2f[col];
#pragma unroll
        for (int i = 0; i < 4; ++i)
            rowsum[i] += fast_tanh(acc[tn][i] + b1v) * w2v;
    }
#pragma unroll
    for (int i = 0; i < 4; ++i) {
        rowsum[i] += __shfl_xor(rowsum[i], 1);
        rowsum[i] += __shfl_xor(rowsum[i], 2);
        rowsum[i] += __shfl_xor(rowsum[i], 4);
        rowsum[i] += __shfl_xor(rowsum[i], 8);
    }
    float bins[3] = {0.f, 0.f, 0.f};
    if (l15 == 0) {
#pragma unroll
        for (int i = 0; i < 4; ++i) {
            int r = row0 + quad * 4 + i;
            if (r < rows) bins[r % 3] += rowsum[i];
        }
    }
#pragma unroll
    for (int b = 0; b < 3; ++b) {   // combine the 4 quads (lanes 0,16,32,48)
        bins[b] += __shfl_xor(bins[b], 16);
        bins[b] += __shfl_xor(bins[b], 32);
    }
    if (lane == 0) {
#pragma unroll
        for (int b = 0; b < 3; ++b) redbuf[wave][b] = bins[b];
    }
    __syncthreads();
    if (tid < 3) {                  // block-level reduce: 3 atomics per block
        float s = 0.f;
#pragma unroll
        for (int w = 0; w < 16; ++w) s += redbuf[w][tid];
        atomicAdd(&wsum[tid], s);
    }
}

// ---------- K8: combine with fused beta = softmax(mean) ----------
__global__ void combine(const _Float16* __restrict__ zb,
                        const float* __restrict__ wsum, float invN,
                        void* __restrict__ out, const int* __restrict__ flags) {
    int idx = blockIdx.x * 256 + threadIdx.x;    // over N*64
    int n = idx >> 6, c4 = (idx & 63) * 4;
    float w0 = wsum[0] * invN, w1 = wsum[1] * invN, w2 = wsum[2] * invN;
    float mx = fmaxf(w0, fmaxf(w1, w2));
    float e0 = __expf(w0 - mx), e1 = __expf(w1 - mx), e2 = __expf(w2 - mx);
    float s = 1.f / (e0 + e1 + e2);
    float b0 = e0 * s, b1 = e1 * s, b2 = e2 * s;
    const _Float16* base = zb + (size_t)n * 768 + c4;
    f16x4 z0 = *reinterpret_cast<const f16x4*>(base);
    f16x4 z1 = *reinterpret_cast<const f16x4*>(base + 256);
    f16x4 z2 = *reinterpret_cast<const f16x4*>(base + 512);
    float v[4];
#pragma unroll
    for (int i = 0; i < 4; ++i)
        v[i] = b0 * (float)z0[i] + b1 * (float)z1[i] + b2 * (float)z2[i];
    if (flags[0]) {
        ushort4 o = {f2bf(v[0]), f2bf(v[1]), f2bf(v[2]), f2bf(v[3])};
        *reinterpret_cast<ushort4*>((unsigned short*)out + (size_t)idx * 4) = o;
    } else {
        f32x4 o = {v[0], v[1], v[2], v[3]};
        *reinterpret_cast<f32x4*>((float*)out + (size_t)idx * 4) = o;
    }
}

extern "C" void kernel_launch(void* const* d_in, const int* in_sizes, int n_in,
                              void* d_out, int out_size, void* d_ws, size_t ws_size,
                              hipStream_t stream) {
    const void* h    = d_in[0];
    const void* e0   = d_in[1];
    const void* e1   = d_in[2];
    const void* e2   = d_in[3];
    const void* W    = d_in[4];
    const void* as   = d_in[5];
    const void* ad   = d_in[6];
    const void* bias = d_in[7];
    const void* w1   = d_in[8];
    const void* b1   = d_in[9];
    const void* w2   = d_in[10];

    const int N = in_sizes[0] / 256;   // 50000
    const int E = in_sizes[1] / 2;     // 400000
    const int M = 3 * N;               // 150000 segments
    const int T4 = (3 * E + 3) / 4;    // edges per strided chunk

    char* ws = (char*)d_ws;
    unsigned short* xw    = (unsigned short*)(ws + XW_OFF);
    _Float16*       zb    = (_Float16*)(ws + ZB_OFF);
    unsigned short* csr   = (unsigned short*)(ws + CSR_OFF);
    int*            rs    = (int*)(ws + RS_OFF);
    int*            cur   = (int*)(ws + CUR_OFF);
    int*            bs    = (int*)(ws + BS_OFF);
    float*          as_   = (float*)(ws + AS_OFF);
    float*          ad_   = (float*)(ws + AD_OFF);
    unsigned short* Wt    = (unsigned short*)(ws + WT_OFF);
    _Float16*       w1t   = (_Float16*)(ws + W1T_OFF);
    float*          asf   = (float*)(ws + ASF_OFF);
    float*          adf   = (float*)(ws + ADF_OFF);
    float*          biasf = (float*)(ws + BIASF_OFF);
    float*          b1f   = (float*)(ws + B1F_OFF);
    float*          w2f   = (float*)(ws + W2F_OFF);
    float*          wsum  = (float*)(ws + WSUM_OFF);
    int*            flags = (int*)(ws + FLAG_OFF);

    // packed-edge scratch overlays the zb region (dead until agg_csr)
    unsigned int* ed = (unsigned int*)(ws + ZB_OFF);   // 3E u32 = 4.8 MB

    probe<<<1, 64, 0, stream>>>((const unsigned short*)h, (const unsigned int*)e0, flags);
    ingest_params<<<907, 256, 0, stream>>>(W, as, ad, bias, w1, b1, w2,
                                           Wt, w1t, asf, adf, biasf, b1f, w2f, flags);

    // CSR build v3
    int nb = (M + 1023) / 1024;                    // 147
    int e4B = (T4 + 255) / 256;                    // 1172
    hipMemsetAsync(cur, 0, M * sizeof(int), stream);
    conv_hist<<<e4B, 256, 0, stream>>>(e0, e1, e2, ed, cur, E, N, T4, flags);
    scan1<<<nb, 1024, 0, stream>>>(cur, rs, bs, M);
    scan2<<<1, 256, 0, stream>>>(bs, rs, nb, M);
    scan3<<<nb, 1024, 0, stream>>>(rs, bs, M);
    hipMemsetAsync(cur, 0, M * sizeof(int), stream);
    scatter<<<e4B, 256, 0, stream>>>(ed, rs, cur, csr, E, N, T4);

    hipMemsetAsync(wsum, 0, 16, stream);

    int gemmBlocks = ((N + 255) / 256) * 2;        // 392
    int aggBlocks  = (N + 3) / 4;                  // 12500
    for (int p = 0; p < 3; ++p) {
        gemm_xw_mfma<<<gemmBlocks, 256, 0, stream>>>(h, Wt + p * 65536, xw,
                                                     asf + p * 256, adf + p * 256,
                                                     as_, ad_, flags, N);
        agg_csr<<<aggBlocks, 256, 0, stream>>>(csr, rs, as_, ad_, xw, biasf, zb, N, p);
    }

    int semBlocks = (M + 255) / 256;               // 586
    sem_w_mfma<<<semBlocks, 1024, 0, stream>>>(zb, w1t, b1f, w2f, wsum, M);
    combine<<<(N * 64 + 255) / 256, 256, 0, stream>>>(zb, wsum, 1.0f / (float)N, d_out, flags);
}